// Round 6
// baseline (3806.145 us; speedup 1.0000x reference)
//
#include <hip/hip_runtime.h>

// ---------------------------------------------------------------------------
// dLSTM R6: L1-bypass (sc0) + explicit depth-4 pipelined A-loads.
// R4/R5 both stuck at 13.6us/phase: compute A-reads were (a) gated through a
// stale-able L1 needing buffer_inv (which forced L3-latency re-fills) and
// (b) compiler-serialized load->MFMA chains. R6: copiers still replicate h
// into per-XCD X buffers (plain stores -> dirty in local L2); compute reads
// X with asm `global_load_dwordx4 ... sc0` (L1 bypassed, served by local L2,
// no cache maintenance anywhere) in an explicit 4-pair-deep software pipeline
// with manual vmcnt + sched_barrier(0) (rule: hipcc hoists MFMA past asm
// waitcnt otherwise). Weights stay register/LDS-resident; barriers counters-only.
// ---------------------------------------------------------------------------

typedef __attribute__((ext_vector_type(8))) short short8;
typedef __attribute__((ext_vector_type(4))) short short4v;
typedef __attribute__((ext_vector_type(4))) float f32x4;
typedef __attribute__((ext_vector_type(4))) unsigned int u32x4;

#define MFMA16(a, b, c) __builtin_amdgcn_mfma_f32_16x16x32_bf16((a), (b), (c), 0, 0, 0)

static constexpr int BATCH = 32;
static constexpr int HID = 2048;
static constexpr int NWG = 256;
static constexpr int NTHR = 512;           // 8 waves
static constexpr int BH = BATCH * HID;     // 65536
static constexpr size_t WMAT = (size_t)8192 * 2048;
static constexpr int LDS_RED_OFF = 139264; // 8 waves * 17 chunks * 1KB
static constexpr int LDS_BYTES = 155648;   // + 16KB reduction

#define AT_ADD(p, v) __hip_atomic_fetch_add((p), (v), __ATOMIC_RELAXED, __HIP_MEMORY_SCOPE_AGENT)
#define AT_LD(p) __hip_atomic_load((p), __ATOMIC_RELAXED, __HIP_MEMORY_SCOPE_AGENT)
#define AT_ST(p, v) __hip_atomic_store((p), (v), __ATOMIC_RELAXED, __HIP_MEMORY_SCOPE_AGENT)

// L1-bypassing (sc0) 16B load; data lands asynchronously -> manual vmcnt.
#define GLA(dst, ab) \
  asm volatile("global_load_dwordx4 %0, %1, off sc0" : "=v"(dst) : "v"(ab) : "memory")

__device__ __forceinline__ unsigned short f2bf(float x) {
  unsigned u = __float_as_uint(x);
  u += 0x7FFFu + ((u >> 16) & 1u);
  return (unsigned short)(u >> 16);
}
__device__ __forceinline__ float sigm(float x) { return 1.f / (1.f + __expf(-x)); }
__device__ __forceinline__ float tanh_(float x) {
  float e = __expf(2.f * x);
  return 1.f - 2.f / (e + 1.f);
}

__global__ void cvt_bf16_k(const float* __restrict__ s, unsigned short* __restrict__ d,
                           long n4) {
  long i = blockIdx.x * (long)blockDim.x + threadIdx.x;
  long st = (long)gridDim.x * blockDim.x;
  for (; i < n4; i += st) {
    float4 v = ((const float4*)s)[i];
    short4v o;
    o.x = (short)f2bf(v.x); o.y = (short)f2bf(v.y);
    o.z = (short)f2bf(v.z); o.w = (short)f2bf(v.w);
    ((short4v*)d)[i] = o;
  }
}

// Wout f32 [2048][2048] -> WoutT bf16 transposed
__global__ void tcvt_k(const float* __restrict__ src, unsigned short* __restrict__ dst) {
  __shared__ float T[64][65];
  const int jb = blockIdx.x * 64, kb = blockIdx.y * 64;
  const int tid = threadIdx.x;
#pragma unroll
  for (int r = 0; r < 4; ++r) {
    const int row = r * 16 + (tid >> 4), c4 = (tid & 15) * 4;
    float4 v = *(const float4*)&src[(size_t)(jb + row) * 2048 + kb + c4];
    T[row][c4] = v.x; T[row][c4 + 1] = v.y; T[row][c4 + 2] = v.z; T[row][c4 + 3] = v.w;
  }
  __syncthreads();
#pragma unroll
  for (int r = 0; r < 4; ++r) {
    const int k = r * 16 + (tid >> 4), j4 = (tid & 15) * 4;
    short4v o;
    o.x = (short)f2bf(T[j4][k]);     o.y = (short)f2bf(T[j4 + 1][k]);
    o.z = (short)f2bf(T[j4 + 2][k]); o.w = (short)f2bf(T[j4 + 3][k]);
    *(short4v*)&dst[(size_t)(kb + k) * 2048 + jb + j4] = o;
  }
}

// Wfp(packed) = A[8192x2048] . Bt[2048x2048]^T ; grid(64,16), 4 waves (2x2)
__global__ void gemm_pack_k(const unsigned short* __restrict__ A,
                            const unsigned short* __restrict__ Bt,
                            unsigned short* __restrict__ Wfp) {
  __shared__ __align__(16) unsigned short As[128][72], Bs[128][72];
  const int tid = threadIdx.x, wv = tid >> 6, lane = tid & 63;
  const int wm = wv >> 1, wn = wv & 1;
  const int g0 = blockIdx.x * 128, k0 = blockIdx.y * 128;
  f32x4 acc[4][4];
#pragma unroll
  for (int i = 0; i < 4; ++i)
#pragma unroll
    for (int j = 0; j < 4; ++j) acc[i][j] = (f32x4){0.f, 0.f, 0.f, 0.f};

  for (int kt = 0; kt < 32; ++kt) {
#pragma unroll
    for (int rr = 0; rr < 4; ++rr) {
      const int row = rr * 32 + (tid >> 3), c8 = (tid & 7) * 8;
      *(short8*)&As[row][c8] = *(const short8*)&A[(size_t)(g0 + row) * 2048 + kt * 64 + c8];
      *(short8*)&Bs[row][c8] = *(const short8*)&Bt[(size_t)(k0 + row) * 2048 + kt * 64 + c8];
    }
    __syncthreads();
#pragma unroll
    for (int kk = 0; kk < 2; ++kk) {
      short8 af[4], bf[4];
#pragma unroll
      for (int mi = 0; mi < 4; ++mi)
        af[mi] = *(const short8*)&As[wm * 64 + mi * 16 + (lane & 15)][kk * 32 + (lane >> 4) * 8];
#pragma unroll
      for (int ni = 0; ni < 4; ++ni)
        bf[ni] = *(const short8*)&Bs[wn * 64 + ni * 16 + (lane & 15)][kk * 32 + (lane >> 4) * 8];
#pragma unroll
      for (int mi = 0; mi < 4; ++mi)
#pragma unroll
        for (int ni = 0; ni < 4; ++ni)
          acc[mi][ni] = MFMA16(af[mi], bf[ni], acc[mi][ni]);
    }
    __syncthreads();
  }
#pragma unroll
  for (int mi = 0; mi < 4; ++mi)
#pragma unroll
    for (int ni = 0; ni < 4; ++ni)
#pragma unroll
      for (int r = 0; r < 4; ++r) {
        const int g = g0 + wm * 64 + mi * 16 + (lane >> 4) * 4 + r;
        const int k = k0 + wn * 64 + ni * 16 + (lane & 15);
        const int gateblk = g >> 11, gcol = g & 2047;
        const int wgp = gcol >> 3, nn = (gcol & 7) + 8 * (gateblk & 1), tile = gateblk >> 1;
        const int kblk = k >> 5, e = k & 7, lane_p = nn + 16 * ((k >> 3) & 3);
        Wfp[(((size_t)(wgp * 2 + tile) * 64 + kblk) * 64 + lane_p) * 8 + e] =
            f2bf(acc[mi][ni][r]);
      }
}

__global__ void pack_W1_k(const float* __restrict__ src, unsigned short* __restrict__ dst) {
  const int bid = blockIdx.x;              // 512: [wg(256)][tile(2)]
  const int wg = bid >> 1, tile = bid & 1;
  const int tid = threadIdx.x;
  __shared__ __align__(16) unsigned short L[16][2056];
  for (int i = tid; i < 16 * 512; i += 256) {
    const int r = i >> 9, c4 = i & 511;
    const int gr = tile * 4096 + (r < 8 ? wg * 8 + r : 2048 + wg * 8 + r - 8);
    float4 v = ((const float4*)(src + (size_t)gr * 2048))[c4];
    short4v o;
    o.x = (short)f2bf(v.x); o.y = (short)f2bf(v.y);
    o.z = (short)f2bf(v.z); o.w = (short)f2bf(v.w);
    *(short4v*)&L[r][c4 * 4] = o;
  }
  __syncthreads();
  short8* dchunks = (short8*)dst;
  const size_t cbase = (size_t)(wg * 2 + tile) * 64;
  for (int c = tid; c < 4096; c += 256) {
    const int lane = c & 63, kblk = c >> 6;
    const int nn = lane & 15, kb = (lane >> 4) << 3;
    short8 v = *(const short8*)&L[nn][kblk * 32 + kb];
    dchunks[(cbase + kblk) * 64 + lane] = v;
  }
}

__global__ void bias_k(const float* __restrict__ Wih, const float* __restrict__ bout,
                       const float* __restrict__ bih, const float* __restrict__ bhh,
                       float* bA0, float* bAf, float* bB) {
  const int g = blockIdx.x * 8 + (threadIdx.x >> 6);
  const int lane = threadIdx.x & 63;
  float s = 0.f;
  for (int i = 0; i < 32; ++i)
    s += Wih[(size_t)g * 2048 + i * 64 + lane] * bout[i * 64 + lane];
  for (int off = 32; off; off >>= 1) s += __shfl_down(s, off);
  if (lane == 0) {
    const float b0 = bih[g] + bhh[g];
    bA0[g] = b0; bAf[g] = b0 + s;
    bB[g] = bih[8192 + g] + bhh[8192 + g];
  }
}

// init: X[8 xcds][2 matrices] = initial h ; zbuf ; c ; ctl counters
__global__ void init_k(const float* __restrict__ h0, const float* __restrict__ c0,
                       unsigned short* hX, unsigned short* zbuf,
                       float* c0f, float* c1f, unsigned* ctl) {
  int i = blockIdx.x * blockDim.x + threadIdx.x;
  if (i < BH) {
    const int e = i & 7, lane = (i >> 3) & 63, kblk = (i >> 9) & 63, mtile = i >> 15;
    const int m = mtile * 16 + (lane & 15);
    const int k = kblk * 32 + ((lane >> 4) << 3) + e;
    const unsigned short v0 = f2bf(h0[m * HID + k]);
    const unsigned short v1 = f2bf(h0[BH + m * HID + k]);
#pragma unroll
    for (int x = 0; x < 8; ++x) {
      hX[(size_t)x * 131072 + i] = v0;
      hX[(size_t)x * 131072 + 65536 + i] = v1;
    }
    zbuf[i] = 0;
    c0f[i] = c0[i];
    c1f[i] = c0[BH + i];
  }
  if (i < 832) ctl[i] = 0u;
}

// ---------------- phase sync: gbar -> copy hG->X[xcd] -> local bar ---------
// ctl layout (u32): [g*32] g<8 gbar groups | [256] master | [288] epoch
//                   [320+x*32] lbar | [576+x*32] elect
__device__ __forceinline__ void phase_sync(unsigned* ctl, int bno, int lbno, int xcc,
                                           int role, int n_x, int n_c, int w, int lane,
                                           const unsigned short* hGm,
                                           unsigned short* Xm) {
  asm volatile("s_waitcnt vmcnt(0)" ::: "memory");
  __syncthreads();
  if (threadIdx.x == 0) {
    const int g = blockIdx.x >> 5;
    unsigned a = AT_ADD(&ctl[g * 32], 1u);
    if (a == (unsigned)(32 * bno - 1)) {
      unsigned m = AT_ADD(&ctl[256], 1u);
      if (m == (unsigned)(8 * bno - 1)) AT_ST(&ctl[288], (unsigned)bno);
    }
    while (AT_LD(&ctl[288]) < (unsigned)bno) __builtin_amdgcn_s_sleep(1);
  }
  __syncthreads();
  // copiers: hG (coherent loads) -> X[xcd] (plain stores -> dirty in own L2)
  if (role < n_c) {
    for (int c = role * 8 + w; c < 128; c += n_c * 8) {
      const unsigned short* s = hGm + c * 512 + lane * 8;
      u32x4 v;
      asm volatile("global_load_dwordx4 %0, %1, off sc0 sc1"
                   : "=v"(v) : "v"((unsigned long long)(size_t)s) : "memory");
      asm volatile("s_waitcnt vmcnt(0)" ::: "memory");
      *(u32x4*)(Xm + c * 512 + lane * 8) = v;
    }
  }
  asm volatile("s_waitcnt vmcnt(0)" ::: "memory");
  __syncthreads();
  if (threadIdx.x == 0) {
    AT_ADD(&ctl[320 + xcc * 32], 1u);
    while (AT_LD(&ctl[320 + xcc * 32]) < (unsigned)(n_x * lbno))
      __builtin_amdgcn_s_sleep(1);
  }
  __syncthreads();
}

// ---- phase body: explicit depth-4 pair-pipelined sc0 A-loads + MFMA -------
#define PHASE_BODY(VARR, NV2, LBASE, CBUF, HOUTP, OUTP, BSEL)                     \
  {                                                                               \
    const unsigned long long a0b = (unsigned long long)(size_t)Asrc +             \
        ((unsigned long long)(ks * 16 * 64 + lane)) * 16ull;                      \
    const unsigned long long a1b = a0b + 65536ull;                                \
    short8 S0[4], S1[4];                                                          \
    _Pragma("unroll")                                                             \
    for (int p = 0; p < 4; ++p) {                                                 \
      GLA(S0[p], a0b + (unsigned long long)p * 1024ull);                          \
      GLA(S1[p], a1b + (unsigned long long)p * 1024ull);                          \
    }                                                                             \
    f32x4 acc00 = {0.f, 0.f, 0.f, 0.f}, acc01 = acc00, acc10 = acc00, acc11 = acc00; \
    _Pragma("unroll")                                                             \
    for (int kk = 0; kk < 16; ++kk) {                                             \
      if (kk < 13) { asm volatile("s_waitcnt vmcnt(6)" ::: "memory"); }           \
      else if (kk == 13) { asm volatile("s_waitcnt vmcnt(4)" ::: "memory"); }     \
      else if (kk == 14) { asm volatile("s_waitcnt vmcnt(2)" ::: "memory"); }     \
      else { asm volatile("s_waitcnt vmcnt(0)" ::: "memory"); }                   \
      __builtin_amdgcn_sched_barrier(0);                                          \
      short8 b0 = VARR[kk];                                                       \
      short8 b1 = (kk < NV2) ? VARR[16 + kk]                                      \
                             : lw[(w * 17 + LBASE + (kk - NV2)) * 64 + lane];     \
      acc00 = MFMA16(S0[kk & 3], b0, acc00);                                      \
      acc01 = MFMA16(S1[kk & 3], b0, acc01);                                      \
      acc10 = MFMA16(S0[kk & 3], b1, acc10);                                      \
      acc11 = MFMA16(S1[kk & 3], b1, acc11);                                      \
      if (kk < 12) {                                                              \
        GLA(S0[kk & 3], a0b + (unsigned long long)(kk + 4) * 1024ull);            \
        GLA(S1[kk & 3], a1b + (unsigned long long)(kk + 4) * 1024ull);            \
      }                                                                           \
    }                                                                             \
    *(f32x4*)&red[((w * 2 + 0) * 64 + lane) * 4] = acc00;                         \
    *(f32x4*)&red[((w * 2 + 1) * 64 + lane) * 4] = acc01;                         \
    __syncthreads();                                                              \
    float gi = 0.f, gf_ = 0.f;                                                    \
    if (tid < 256) {                                                              \
      const int b = tid >> 3, cc = tid & 7, m = b >> 4, br = b & 15;              \
      const int reg = br & 3, lb = (br >> 2) << 4;                                \
      _Pragma("unroll")                                                           \
      for (int ww = 0; ww < 8; ++ww) {                                            \
        gi  += red[((ww * 2 + m) * 64 + lb + cc) * 4 + reg];                      \
        gf_ += red[((ww * 2 + m) * 64 + lb + cc + 8) * 4 + reg];                  \
      }                                                                           \
    }                                                                             \
    __syncthreads();                                                              \
    *(f32x4*)&red[((w * 2 + 0) * 64 + lane) * 4] = acc10;                         \
    *(f32x4*)&red[((w * 2 + 1) * 64 + lane) * 4] = acc11;                         \
    __syncthreads();                                                              \
    if (tid < 256) {                                                              \
      const int b = tid >> 3, cc = tid & 7, m = b >> 4, br = b & 15;              \
      const int reg = br & 3, lb = (br >> 2) << 4;                                \
      float gg = 0.f, go = 0.f;                                                   \
      _Pragma("unroll")                                                           \
      for (int ww = 0; ww < 8; ++ww) {                                            \
        gg += red[((ww * 2 + m) * 64 + lb + cc) * 4 + reg];                       \
        go += red[((ww * 2 + m) * 64 + lb + cc + 8) * 4 + reg];                   \
      }                                                                           \
      const int col = wg * 8 + cc;                                                \
      gi  += (BSEL)[col];                                                         \
      gf_ += (BSEL)[2048 + col];                                                  \
      gg  += (BSEL)[4096 + col];                                                  \
      go  += (BSEL)[6144 + col];                                                  \
      const float iv = sigm(gi), fv = sigm(gf_), gv = tanh_(gg), ov = sigm(go);   \
      const float cold = (CBUF)[b * HID + col];                                   \
      const float cnew = fv * cold + iv * gv;                                     \
      const float hnew = ov * tanh_(cnew);                                        \
      (CBUF)[b * HID + col] = cnew;                                               \
      const int kblk = col >> 5, lh = (col >> 3) & 3, e = col & 7;                \
      const int lane_p = (b & 15) | (lh << 4), mt = b >> 4;                       \
      const unsigned hv = (unsigned)f2bf(hnew);                                   \
      unsigned long long ha = (unsigned long long)(size_t)                        \
          ((HOUTP) + ((size_t)(mt * 64 + kblk) * 64 + lane_p) * 8 + e);           \
      asm volatile("global_store_short %0, %1, off sc0 sc1"                       \
                   :: "v"(ha), "v"(hv) : "memory");                               \
      if (OUTP) ((float*)(OUTP))[b * HID + col] = hnew;                           \
    }                                                                             \
  }

__global__ __launch_bounds__(NTHR, 1) void lstm_persist(
    const unsigned short* __restrict__ Wfp, const unsigned short* __restrict__ Wh0p,
    const unsigned short* __restrict__ Wi1p, const unsigned short* __restrict__ Wh1p,
    const float* __restrict__ bA0, const float* __restrict__ bAf,
    const float* __restrict__ bB,
    unsigned short* hX,      // [8][2][65536] per-XCD cached copies
    unsigned short* hG,      // [2][65536] device-coherent staging
    const unsigned short* zbuf,
    float* c0f, float* c1f, float* __restrict__ out, int T, unsigned* ctl) {
  extern __shared__ __align__(16) char smem[];
  short8* lw = (short8*)smem;
  float* red = (float*)(smem + LDS_RED_OFF);
  const int wg = blockIdx.x, tid = threadIdx.x;
  const int w = tid >> 6, lane = tid & 63, ks = w & 3;
  const int xcc = (int)(__builtin_amdgcn_s_getreg((20) | (0 << 6) | (31 << 11)) & 7);
  const unsigned short* M0 = (w < 4) ? Wfp : Wh0p;
  const unsigned short* M1 = (w < 4) ? Wi1p : Wh1p;

  // election (physical-XCD role assignment)
  if (tid == 0) *(int*)red = (int)AT_ADD(&ctl[576 + xcc * 32], 1u);

  // weight prologue: 47 reg chunks + 17 LDS chunks per wave
  short8 v0[24], v1[23];
  {
    const short8* m0c = (const short8*)M0;
    const short8* m1c = (const short8*)M1;
#pragma unroll
    for (int c = 0; c < 24; ++c)
      v0[c] = m0c[(((size_t)(wg * 2 + (c >> 4)) * 64) + ks * 16 + (c & 15)) * 64 + lane];
#pragma unroll
    for (int c = 24; c < 32; ++c)
      lw[(w * 17 + (c - 24)) * 64 + lane] =
          m0c[(((size_t)(wg * 2 + (c >> 4)) * 64) + ks * 16 + (c & 15)) * 64 + lane];
#pragma unroll
    for (int c = 0; c < 23; ++c)
      v1[c] = m1c[(((size_t)(wg * 2 + (c >> 4)) * 64) + ks * 16 + (c & 15)) * 64 + lane];
#pragma unroll
    for (int c = 23; c < 32; ++c)
      lw[(w * 17 + 8 + (c - 23)) * 64 + lane] =
          m1c[(((size_t)(wg * 2 + (c >> 4)) * 64) + ks * 16 + (c & 15)) * 64 + lane];
  }
  __syncthreads();
  const int role = *(int*)red;
  unsigned short* Xh0 = hX + (size_t)xcc * 131072;
  unsigned short* Xh1 = Xh0 + 65536;

  // gbar #1: all elections done, weights loaded
  asm volatile("s_waitcnt vmcnt(0)" ::: "memory");
  __syncthreads();
  if (tid == 0) {
    const int g = blockIdx.x >> 5;
    unsigned a = AT_ADD(&ctl[g * 32], 1u);
    if (a == 31u) {
      unsigned m = AT_ADD(&ctl[256], 1u);
      if (m == 7u) AT_ST(&ctl[288], 1u);
    }
    while (AT_LD(&ctl[288]) < 1u) __builtin_amdgcn_s_sleep(1);
    *(int*)red = (int)AT_LD(&ctl[576 + xcc * 32]);
  }
  __syncthreads();
  const int n_x = *(int*)red;
  const int n_c = n_x < 16 ? n_x : 16;
  __syncthreads();

  int bno = 2, lbno = 1;
  for (int t = 0; t < T; ++t) {
    {  // phase A: gates0 = Wfused*h1(t-1) + Whh0*h0(t-1) -> h0(t), c0
      const unsigned short* Asrc = (w < 4) ? ((t == 0) ? zbuf : Xh1) : Xh0;
      const float* bsel = (t == 0) ? bA0 : bAf;
      PHASE_BODY(v0, 8, 0, c0f, hG, (float*)nullptr, bsel)
    }
    phase_sync(ctl, bno++, lbno++, xcc, role, n_x, n_c, w, lane, hG, Xh0);
    {  // phase B: gates1 = Wih1*h0(t) + Whh1*h1(t-1) -> h1(t), c1, out(t)
      const unsigned short* Asrc = (w < 4) ? Xh0 : Xh1;
      PHASE_BODY(v1, 7, 8, c1f, hG + 65536, out + (size_t)t * BH, bB)
    }
    phase_sync(ctl, bno++, lbno++, xcc, role, n_x, n_c, w, lane, hG + 65536, Xh1);
  }
}

extern "C" void kernel_launch(void* const* d_in, const int* in_sizes, int n_in,
                              void* d_out, int out_size, void* d_ws, size_t ws_size,
                              hipStream_t stream) {
  const float* h0 = (const float*)d_in[0];
  const float* c0 = (const float*)d_in[1];
  const float* Wih = (const float*)d_in[2];
  const float* Whh = (const float*)d_in[3];
  const float* bih = (const float*)d_in[4];
  const float* bhh = (const float*)d_in[5];
  const float* Wout = (const float*)d_in[6];
  const float* bout = (const float*)d_in[7];
  float* out = (float*)d_out;
  const int T = out_size / BH;

  unsigned short* Wfp = (unsigned short*)d_ws;
  unsigned short* Wh0p = Wfp + WMAT;
  unsigned short* Wi1p = Wfp + 2 * WMAT;
  unsigned short* Wh1p = Wfp + 3 * WMAT;
  unsigned short* tmpA = Wi1p;    // alias, dead after gemm_pack_k
  unsigned short* WoutT = Wh1p;   // alias, dead after gemm_pack_k
  unsigned short* S = Wfp + 4 * WMAT;
  unsigned short* hX = S;                    // 8*2*65536 = 1,048,576
  unsigned short* hG = S + 1048576;          // 2*65536
  unsigned short* zbuf = S + 1179648;        // 65536
  float* F = (float*)(S + 1245184);
  float* c0f = F;
  float* c1f = F + 65536;
  float* bA0 = F + 131072;
  float* bAf = F + 139264;
  float* bB = F + 147456;
  unsigned* ctl = (unsigned*)(F + 155648);   // 832 u32

  cvt_bf16_k<<<2048, 256, 0, stream>>>(Wih, tmpA, (long)(WMAT / 4));
  tcvt_k<<<dim3(32, 32), 256, 0, stream>>>(Wout, WoutT);
  gemm_pack_k<<<dim3(64, 16), 256, 0, stream>>>(tmpA, WoutT, Wfp);
  pack_W1_k<<<512, 256, 0, stream>>>(Whh, Wh0p);
  pack_W1_k<<<512, 256, 0, stream>>>(Wih + WMAT, Wi1p);
  pack_W1_k<<<512, 256, 0, stream>>>(Whh + WMAT, Wh1p);
  bias_k<<<1024, 512, 0, stream>>>(Wih, bout, bih, bhh, bA0, bAf, bB);
  init_k<<<256, 256, 0, stream>>>(h0, c0, hX, zbuf, c0f, c1f, ctl);

  (void)hipFuncSetAttribute((const void*)lstm_persist,
                            hipFuncAttributeMaxDynamicSharedMemorySize, LDS_BYTES);
  lstm_persist<<<NWG, NTHR, LDS_BYTES, stream>>>(Wfp, Wh0p, Wi1p, Wh1p,
                                                 bA0, bAf, bB,
                                                 hX, hG, zbuf, c0f, c1f, out, T, ctl);
}